// Round 11
// baseline (368.520 us; speedup 1.0000x reference)
//
#include <hip/hip_runtime.h>
#include <math.h>
#include <stdint.h>

// B=8,S=2048,D=512,I=1024,E=8,K=2,SH=2048 ; T=16384 tokens
#define T_TOK 16384
#define DDIM  512
#define IDIM  1024
#define NEXP  8
#define SHDIM 2048
#define MPAD  34816                // routed rows padded to 256-tiles: 136 tiles
#define NMT_R 136
#define GBLK  256                  // k_gate blocks (64 tokens each)

typedef unsigned short u16;
typedef short bf16x8 __attribute__((ext_vector_type(8)));
typedef float f32x4 __attribute__((ext_vector_type(4)));

__device__ __forceinline__ u16 f2bf(float f) {
    unsigned u = __float_as_uint(f);
    u += 0x7FFF + ((u >> 16) & 1);   // round-to-nearest-even
    return (u16)(u >> 16);
}
__device__ __forceinline__ float bf2f(u16 h) {
    return __uint_as_float((unsigned)h << 16);
}

__device__ __forceinline__ void gload_lds16(const void* g, void* l) {
    __builtin_amdgcn_global_load_lds(
        (const __attribute__((address_space(1))) void*)g,
        (__attribute__((address_space(3))) void*)l, 16, 0, 0);
}

// XCD-chunked bijective block swizzle (T1); nwg % 8 == 0 for all our grids.
__device__ __forceinline__ int xcd_swz(int id, int nwg) {
    return (id & 7) * (nwg >> 3) + (id >> 3);
}

// 16B-slot swizzle for 128B rows (8 slots): rows r..r+15 cover each slot 2x (free).
__device__ __forceinline__ int fsw(int r) { return (r >> 1) & 7; }

// ---------------- routing ----------------
__global__ void k_zero(int* cursors) {
    int i = threadIdx.x;
    if (i < NEXP) cursors[i] = 0;
}

// 64 tokens/block, 4 waves. No global atomics; fuses x->bf16 (writes xb).
__global__ __launch_bounds__(256) void k_gate(
    const float* __restrict__ x, const float* __restrict__ gw,
    int* __restrict__ topi, float* __restrict__ wts,
    int* __restrict__ pcnt, float* __restrict__ pps, u16* __restrict__ xb)
{
    __shared__ int   cnt[NEXP];
    __shared__ float ps[NEXP];
    const int tid = threadIdx.x;
    if (tid < NEXP) { cnt[tid] = 0; ps[tid] = 0.f; }
    __syncthreads();
    const int wid = tid >> 6, lane = tid & 63;

    const float4* gw4 = (const float4*)gw;
    float4 g0[NEXP], g1[NEXP];
#pragma unroll
    for (int e = 0; e < NEXP; e++) {
        g0[e] = gw4[e * 128 + lane];
        g1[e] = gw4[e * 128 + 64 + lane];
    }

    const int t0 = blockIdx.x * 64 + wid * 16;
    for (int u = 0; u < 16; u++) {
        int t = t0 + u;
        const float4* xr4 = (const float4*)(x + (size_t)t * DDIM);
        float4 v0 = xr4[lane];
        float4 v1 = xr4[64 + lane];
        ushort4 o0 = { f2bf(v0.x), f2bf(v0.y), f2bf(v0.z), f2bf(v0.w) };
        ushort4 o1 = { f2bf(v1.x), f2bf(v1.y), f2bf(v1.z), f2bf(v1.w) };
        ushort4* xbo = (ushort4*)(xb + (size_t)t * DDIM);
        xbo[lane] = o0;
        xbo[64 + lane] = o1;
        float acc[NEXP];
#pragma unroll
        for (int e = 0; e < NEXP; e++) {
            acc[e] = v0.x * g0[e].x + v0.y * g0[e].y + v0.z * g0[e].z + v0.w * g0[e].w
                   + v1.x * g1[e].x + v1.y * g1[e].y + v1.z * g1[e].z + v1.w * g1[e].w;
        }
#pragma unroll
        for (int e = 0; e < NEXP; e++) {
#pragma unroll
            for (int off = 32; off; off >>= 1) acc[e] += __shfl_xor(acc[e], off, 64);
        }
        if (lane == 0) {
            float s[NEXP];
#pragma unroll
            for (int e = 0; e < NEXP; e++) s[e] = 1.f / (1.f + expf(-acc[e]));
            int i1 = 0; float v1s = s[0];
#pragma unroll
            for (int e = 1; e < NEXP; e++) if (s[e] > v1s) { v1s = s[e]; i1 = e; }
            int i2 = -1; float v2s = -1.f;
#pragma unroll
            for (int e = 0; e < NEXP; e++) if (e != i1 && s[e] > v2s) { v2s = s[e]; i2 = e; }
            float inv = 1.f / (v1s + v2s);
            float wa = v1s * inv, wb = v2s * inv;  // ROUTE_SCALE = 1.0
            topi[2 * t] = i1; topi[2 * t + 1] = i2;
            wts[2 * t] = wa;  wts[2 * t + 1] = wb;
            atomicAdd(&cnt[i1], 1); atomicAdd(&cnt[i2], 1);   // LDS atomics
            atomicAdd(&ps[i1], wa); atomicAdd(&ps[i2], wb);
        }
    }
    __syncthreads();
    if (tid < NEXP) {
        pcnt[blockIdx.x * NEXP + tid] = cnt[tid];
        pps[blockIdx.x * NEXP + tid]  = ps[tid];
    }
}

// Reduce per-block partials; 256-padded exclusive prefix; aux loss.
__global__ void k_scan(const int* __restrict__ pcnt, const float* __restrict__ pps,
                       int* __restrict__ off_pad, float* __restrict__ out_loss)
{
    __shared__ int   scnt[8][NEXP];
    __shared__ float sps[8][NEXP];
    int tid = threadIdx.x;
    if (tid < 64) {
        int e = tid & 7, part = tid >> 3;
        int c = 0; float p = 0.f;
        for (int b = part * 32; b < part * 32 + 32; b++) {
            c += pcnt[b * NEXP + e];
            p += pps[b * NEXP + e];
        }
        scnt[part][e] = c; sps[part][e] = p;
    }
    __syncthreads();
    if (tid == 0) {
        int off = 0; float L = 0.f;
        for (int e = 0; e < NEXP; e++) {
            int c = 0; float p = 0.f;
            for (int q = 0; q < 8; q++) { c += scnt[q][e]; p += sps[q][e]; }
            off_pad[e] = off;
            off += (c + 255) & ~255;       // pad segments to 256 (M-tile)
            float f = (float)NEXP * (float)c / (float)(2 * T_TOK);
            L += f * (p / (float)T_TOK);
        }
        off_pad[NEXP] = off;
        out_loss[0] = L;
    }
}

// fills perm with -1; also zeroes the 512-elem bf16 zero-page
__global__ void k_fillperm(int* __restrict__ perm, u16* __restrict__ zpad) {
    int i = blockIdx.x * blockDim.x + threadIdx.x;
    if (i < MPAD) perm[i] = -1;
    if (blockIdx.x == 0 && threadIdx.x < 256) ((unsigned*)zpad)[threadIdx.x] = 0u;
}

// 256 tokens/block: LDS histogram -> one global atomicAdd per expert per block.
__global__ __launch_bounds__(256) void k_scatter(
    const int* __restrict__ topi, const float* __restrict__ wts,
    const int* __restrict__ off_pad, int* __restrict__ cursors,
    int* __restrict__ perm, float* __restrict__ pw, int* __restrict__ inv)
{
    __shared__ int lcnt[NEXP];
    __shared__ int lbase[NEXP];
    int tid = threadIdx.x;
    if (tid < NEXP) lcnt[tid] = 0;
    __syncthreads();
    int t = blockIdx.x * 256 + tid;
    int e0 = topi[2 * t], e1 = topi[2 * t + 1];
    int p0 = atomicAdd(&lcnt[e0], 1);
    int p1 = atomicAdd(&lcnt[e1], 1);
    __syncthreads();
    if (tid < NEXP) lbase[tid] = atomicAdd(&cursors[tid], lcnt[tid]);
    __syncthreads();
    int s0 = off_pad[e0] + lbase[e0] + p0;
    int s1 = off_pad[e1] + lbase[e1] + p1;
    perm[s0] = t; pw[s0] = wts[2 * t];
    perm[s1] = t; pw[s1] = wts[2 * t + 1];
    inv[2 * t] = s0; inv[2 * t + 1] = s1;
}

// Transpose + bf16 cast with row remap: dst row = (gc>>lg)*rmul + (gc & ((1<<lg)-1)) + radd.
// grid (C/64, R/64, nmat); dst slab stride = zrows*R
__global__ __launch_bounds__(256) void k_transpose(const float* __restrict__ src,
                                                   u16* __restrict__ dst, int R, int C,
                                                   int lg, int rmul, int radd, int zrows)
{
    __shared__ u16 t[64][68];
    const float* s = src + (size_t)blockIdx.z * R * C;
    u16* d = dst + (size_t)blockIdx.z * zrows * R;
    int r0 = blockIdx.y * 64, c0 = blockIdx.x * 64;
    int tid = threadIdx.x;
    int lr = tid >> 4, lc = (tid & 15) * 4;
#pragma unroll
    for (int u = 0; u < 4; u++) {
        int r = lr + u * 16;
        float4 v = *(const float4*)&s[(size_t)(r0 + r) * C + c0 + lc];
        t[lc + 0][r] = f2bf(v.x);
        t[lc + 1][r] = f2bf(v.y);
        t[lc + 2][r] = f2bf(v.z);
        t[lc + 3][r] = f2bf(v.w);
    }
    __syncthreads();
    int wr = tid >> 4, wc = (tid & 15) * 4;
#pragma unroll
    for (int u = 0; u < 4; u++) {
        int c = wr + u * 16;
        int gc = c0 + c;
        int rp = (gc >> lg) * rmul + (gc & ((1 << lg) - 1)) + radd;
        ushort4 o = { t[c][wc], t[c][wc + 1], t[c][wc + 2], t[c][wc + 3] };
        *(ushort4*)&d[(size_t)rp * R + r0 + wc] = o;
    }
}

// ======== 8-phase-style GEMM core: 256(M)x128(Brows) tile, 8 waves, BK=64 ========
// 3 buffers x (A 32KB | B 16KB) = 144KB. Per K-tile: 2 phases, each
// {ds_read frags ; 3 gloads of tile t+2 ; [vmcnt(6) in phase 1] ; barrier ;
//  lgkmcnt(0)+sched_barrier ; setprio(1) 16 MFMA setprio(0) ; barrier}.
// EPI: 0 = SwiGLU->H bf16 (B = interleaved w1|w3, 16-granular)
//      1 = out = C + bias2 (f32)
//      2 = ytmp = bf16(C)
template<int K, int EPI, bool ROUTED, bool BIAS>
__global__ __launch_bounds__(512, 2) void k_mm(
    const u16* __restrict__ A, const u16* __restrict__ Bt,
    const float* __restrict__ bias1, const float* __restrict__ bias3,
    u16* __restrict__ H, int ldh, float* __restrict__ outp,
    const int* __restrict__ off_pad, const int* __restrict__ perm,
    const u16* __restrict__ zpad, int bstride)
{
    __shared__ __align__(16) unsigned char smem[3 * 49152];
    const int nwg = gridDim.x * gridDim.y;
    const int id  = xcd_swz(blockIdx.y * gridDim.x + blockIdx.x, nwg);
    const int m0  = (id / gridDim.x) * 256;
    const int ntb = id % gridDim.x;
    const int n0r = ntb * 128;                 // B-row base
    if (ROUTED && m0 >= off_pad[NEXP]) return;
    const u16* B = Bt;
    if (ROUTED) {
        int e = 0;
        while (off_pad[e + 1] <= m0) e++;
        B += (size_t)e * bstride;
    }
    const int tid = threadIdx.x;
    const int wid = tid >> 6, lane = tid & 63;
    const int wm = wid >> 2, wn = wid & 3;
    const int fr = lane & 15, hi = lane >> 4;

    // staging sources: sweep = 64 rows x 64K (8KB, 1 gload/thread). A 4 sweeps, B 2.
    const u16* asrc[4]; const u16* bsrc[2];
    const int srow = tid >> 3, sslot = tid & 7;
#pragma unroll
    for (int s = 0; s < 4; s++) {
        int r = s * 64 + srow;
        int goff = (sslot ^ fsw(r)) * 8;
        if (EPI == 0 && ROUTED) {
            int tok = perm[m0 + r];
            asrc[s] = (tok >= 0 ? A + (size_t)tok * K : zpad) + goff;
        } else {
            asrc[s] = A + (size_t)(m0 + r) * K + goff;
        }
    }
#pragma unroll
    for (int s = 0; s < 2; s++) {
        int r = s * 64 + srow;
        bsrc[s] = B + (size_t)(n0r + r) * K + (sslot ^ fsw(r)) * 8;
    }
    const int dstT = tid * 16;

    // fragment LDS byte offsets (slot-swizzled read side)
    int aoff[2][4][2], boff[2][2];
#pragma unroll
    for (int h = 0; h < 2; h++)
#pragma unroll
        for (int i = 0; i < 4; i++) {
            int ar = wm * 128 + h * 64 + i * 16 + fr;
#pragma unroll
            for (int s = 0; s < 2; s++)
                aoff[h][i][s] = ar * 128 + (((s * 4 + hi) ^ fsw(ar)) << 4);
        }
#pragma unroll
    for (int j = 0; j < 2; j++) {
        int br = wn * 32 + j * 16 + fr;
#pragma unroll
        for (int s = 0; s < 2; s++)
            boff[j][s] = 32768 + br * 128 + (((s * 4 + hi) ^ fsw(br)) << 4);
    }

    f32x4 acc[8][2];
#pragma unroll
    for (int i = 0; i < 8; i++)
#pragma unroll
        for (int j = 0; j < 2; j++) acc[i][j] = {0.f, 0.f, 0.f, 0.f};

    const int NT = K / 64;
    // prologue: stage tiles 0,1 (6 gloads each)
#pragma unroll
    for (int t = 0; t < 2; t++) {
        unsigned char* bb = smem + t * 49152;
#pragma unroll
        for (int s = 0; s < 4; s++) gload_lds16(asrc[s] + t * 64, bb + s * 8192 + dstT);
#pragma unroll
        for (int s = 0; s < 2; s++) gload_lds16(bsrc[s] + t * 64, bb + 32768 + s * 8192 + dstT);
    }
    asm volatile("s_waitcnt vmcnt(6)" ::: "memory");   // tile 0 landed (tile 1 in flight)
    __builtin_amdgcn_s_barrier();

    int bufc = 0;
    for (int t = 0; t < NT; t++) {
        const unsigned char* cb = smem + bufc * 49152;
        int bufn = bufc + 2; if (bufn >= 3) bufn -= 3;
        unsigned char* nb = smem + bufn * 49152;
        const int k2 = (t + 2) * 64;
        bf16x8 bv[2][2];

        // ---- phase 0: Mhalf0.  12 ds_reads ; 3 gloads ; barrier ; 16 MFMA ; barrier
        {
            bf16x8 av[4][2];
#pragma unroll
            for (int j = 0; j < 2; j++)
#pragma unroll
                for (int s = 0; s < 2; s++) bv[j][s] = *(const bf16x8*)(cb + boff[j][s]);
#pragma unroll
            for (int i = 0; i < 4; i++)
#pragma unroll
                for (int s = 0; s < 2; s++) av[i][s] = *(const bf16x8*)(cb + aoff[0][i][s]);
            if (t + 2 < NT) {
#pragma unroll
                for (int s = 0; s < 3; s++) gload_lds16(asrc[s] + k2, nb + s * 8192 + dstT);
            }
            __builtin_amdgcn_s_barrier();
            asm volatile("s_waitcnt lgkmcnt(0)" ::: "memory");
            __builtin_amdgcn_sched_barrier(0);
            __builtin_amdgcn_s_setprio(1);
#pragma unroll
            for (int s = 0; s < 2; s++)
#pragma unroll
                for (int i = 0; i < 4; i++)
#pragma unroll
                    for (int j = 0; j < 2; j++)
                        acc[i][j] = __builtin_amdgcn_mfma_f32_16x16x32_bf16(av[i][s], bv[j][s], acc[i][j], 0, 0, 0);
            __builtin_amdgcn_s_setprio(0);
            __builtin_amdgcn_sched_barrier(0);
            __builtin_amdgcn_s_barrier();
        }

        // ---- phase 1: Mhalf1.  8 ds_reads ; 3 gloads ; vmcnt(6) ; barrier ; 16 MFMA ; barrier
        {
            bf16x8 av[4][2];
#pragma unroll
            for (int i = 0; i < 4; i++)
#pragma unroll
                for (int s = 0; s < 2; s++) av[i][s] = *(const bf16x8*)(cb + aoff[1][i][s]);
            if (t + 2 < NT) {
                gload_lds16(asrc[3] + k2, nb + 3 * 8192 + dstT);
#pragma unroll
                for (int s = 0; s < 2; s++) gload_lds16(bsrc[s] + k2, nb + 32768 + s * 8192 + dstT);
                asm volatile("s_waitcnt vmcnt(6)" ::: "memory");   // tile t+1 landed; t+2 in flight
            } else if (t + 2 == NT) {
                asm volatile("s_waitcnt vmcnt(0)" ::: "memory");   // drain before final tile
            }
            __builtin_amdgcn_s_barrier();
            asm volatile("s_waitcnt lgkmcnt(0)" ::: "memory");
            __builtin_amdgcn_sched_barrier(0);
            __builtin_amdgcn_s_setprio(1);
#pragma unroll
            for (int s = 0; s < 2; s++)
#pragma unroll
                for (int i = 0; i < 4; i++)
#pragma unroll
                    for (int j = 0; j < 2; j++)
                        acc[4 + i][j] = __builtin_amdgcn_mfma_f32_16x16x32_bf16(av[i][s], bv[j][s], acc[4 + i][j], 0, 0, 0);
            __builtin_amdgcn_s_setprio(0);
            __builtin_amdgcn_sched_barrier(0);
            __builtin_amdgcn_s_barrier();
        }
        bufc++; if (bufc >= 3) bufc -= 3;
    }

    // ---- epilogue
    if (EPI == 0) {
        // SwiGLU: acc[i][0] = C1, acc[i][1] = C3 for the same 16 h-cols
        int hcol = ntb * 64 + wn * 16 + fr;
        float b1 = BIAS ? bias1[hcol] : 0.f;
        float b3 = BIAS ? bias3[hcol] : 0.f;
#pragma unroll
        for (int i = 0; i < 8; i++) {
#pragma unroll
            for (int r = 0; r < 4; r++) {
                int row = m0 + wm * 128 + i * 16 + hi * 4 + r;
                float v1 = acc[i][0][r] + b1;
                float v3 = acc[i][1][r] + b3;
                float hv = (v1 / (1.f + __expf(-v1))) * v3;
                H[(size_t)row * ldh + hcol] = f2bf(hv);
            }
        }
    } else {
#pragma unroll
        for (int i = 0; i < 8; i++) {
#pragma unroll
            for (int r = 0; r < 4; r++) {
                int row = m0 + wm * 128 + i * 16 + hi * 4 + r;
#pragma unroll
                for (int j = 0; j < 2; j++) {
                    int col = n0r + wn * 32 + j * 16 + fr;
                    float v = acc[i][j][r];
                    if (EPI == 1) outp[(size_t)row * DDIM + col] = v + bias1[col];
                    else          H[(size_t)row * DDIM + col] = f2bf(v);
                }
            }
        }
    }
}

// out[t] += wts[2t]*ytmp[inv[2t]] + wts[2t+1]*ytmp[inv[2t+1]]
__global__ __launch_bounds__(256) void k_combine(
    const u16* __restrict__ ytmp, const int* __restrict__ inv,
    const float* __restrict__ wts, float* __restrict__ out)
{
    int idx = blockIdx.x * 256 + threadIdx.x;
    int t = idx >> 7;
    int c = (idx & 127) * 4;
    int s0 = inv[2 * t], s1 = inv[2 * t + 1];
    float w0 = wts[2 * t], w1 = wts[2 * t + 1];
    ushort4 a = *(const ushort4*)&ytmp[(size_t)s0 * DDIM + c];
    ushort4 b = *(const ushort4*)&ytmp[(size_t)s1 * DDIM + c];
    float4 o = *(float4*)&out[(size_t)t * DDIM + c];
    o.x += w0 * bf2f(a.x) + w1 * bf2f(b.x);
    o.y += w0 * bf2f(a.y) + w1 * bf2f(b.y);
    o.z += w0 * bf2f(a.z) + w1 * bf2f(b.z);
    o.w += w0 * bf2f(a.w) + w1 * bf2f(b.w);
    *(float4*)&out[(size_t)t * DDIM + c] = o;
}

// ---------------- launch ----------------
extern "C" void kernel_launch(void* const* d_in, const int* in_sizes, int n_in,
                              void* d_out, int out_size, void* d_ws, size_t ws_size,
                              hipStream_t stream)
{
    const float* x   = (const float*)d_in[0];
    const float* gw  = (const float*)d_in[1];
    const float* w1  = (const float*)d_in[2];
    const float* w2  = (const float*)d_in[3];
    const float* w3  = (const float*)d_in[4];
    const float* sw1 = (const float*)d_in[5];
    const float* sb1 = (const float*)d_in[6];
    const float* sw2 = (const float*)d_in[7];
    const float* sb2 = (const float*)d_in[8];
    const float* sw3 = (const float*)d_in[9];
    const float* sb3 = (const float*)d_in[10];
    float* out = (float*)d_out;

    char* ws = (char*)d_ws;
    size_t off = 0;
    int*   topi    = (int*)(ws + off);   off += (size_t)2 * T_TOK * 4;
    float* wts     = (float*)(ws + off); off += (size_t)2 * T_TOK * 4;
    int*   perm    = (int*)(ws + off);   off += (size_t)MPAD * 4;
    float* pw      = (float*)(ws + off); off += (size_t)MPAD * 4;
    int*   cursors = (int*)(ws + off);   off += 256;
    int*   off_pad = (int*)(ws + off);   off += 256;
    int*   pcnt    = (int*)(ws + off);   off += (size_t)GBLK * NEXP * 4;
    float* pps     = (float*)(ws + off); off += (size_t)GBLK * NEXP * 4;
    int*   inv     = (int*)(ws + off);   off += (size_t)2 * T_TOK * 4;
    u16*   zpad    = (u16*)(ws + off);   off += 1024;
    u16*   xb      = (u16*)(ws + off);   off += (size_t)T_TOK * DDIM * 2;
    u16*   ytmp    = (u16*)(ws + off);   off += (size_t)MPAD * DDIM * 2;
    u16*   w13Ts   = (u16*)(ws + off);   off += (size_t)2 * SHDIM * DDIM * 2;          // [4096][512]
    u16*   w13Tr   = (u16*)(ws + off);   off += (size_t)NEXP * 2 * IDIM * DDIM * 2;    // [8][2048][512]
    u16*   w2T     = (u16*)(ws + off);   off += (size_t)NEXP * DDIM * IDIM * 2;
    u16*   sw2T    = (u16*)(ws + off);   off += (size_t)DDIM * SHDIM * 2;
    u16*   hb      = (u16*)(ws + off);   off += (size_t)MPAD * IDIM * 2;  // holds shared h (67MB) too

    // routing
    k_zero<<<1, 64, 0, stream>>>(cursors);
    k_gate<<<GBLK, 256, 0, stream>>>(x, gw, topi, wts, pcnt, pps, xb);
    k_scan<<<1, 64, 0, stream>>>(pcnt, pps, off_pad, out + (size_t)T_TOK * DDIM);
    k_fillperm<<<MPAD / 256, 256, 0, stream>>>(perm, zpad);
    k_scatter<<<T_TOK / 256, 256, 0, stream>>>(topi, wts, off_pad, cursors, perm, pw, inv);

    // weights: bf16 transposes. w13T interleaved at 16-col granularity (w1|w3 per 32 rows).
    k_transpose<<<dim3(SHDIM / 64, DDIM / 64, 1), 256, 0, stream>>>(sw1, w13Ts, DDIM, SHDIM, 4, 32, 0,  2 * SHDIM);
    k_transpose<<<dim3(SHDIM / 64, DDIM / 64, 1), 256, 0, stream>>>(sw3, w13Ts, DDIM, SHDIM, 4, 32, 16, 2 * SHDIM);
    k_transpose<<<dim3(IDIM / 64, DDIM / 64, NEXP), 256, 0, stream>>>(w1, w13Tr, DDIM, IDIM, 4, 32, 0,  2 * IDIM);
    k_transpose<<<dim3(IDIM / 64, DDIM / 64, NEXP), 256, 0, stream>>>(w3, w13Tr, DDIM, IDIM, 4, 32, 16, 2 * IDIM);
    k_transpose<<<dim3(DDIM / 64, IDIM / 64, NEXP), 256, 0, stream>>>(w2, w2T, IDIM, DDIM, 6, 64, 0, DDIM);
    k_transpose<<<dim3(DDIM / 64, SHDIM / 64, 1), 256, 0, stream>>>(sw2, sw2T, SHDIM, DDIM, 6, 64, 0, DDIM);

    // shared expert: h -> hb[16384][2048], out = h@sw2 + b2
    k_mm<DDIM, 0, false, true><<<dim3(SHDIM / 64, T_TOK / 256), 512, 0, stream>>>(
        xb, w13Ts, sb1, sb3, hb, SHDIM, nullptr, nullptr, nullptr, nullptr, 0);
    k_mm<SHDIM, 1, false, false><<<dim3(DDIM / 128, T_TOK / 256), 512, 0, stream>>>(
        hb, sw2T, sb2, nullptr, nullptr, 0, out, nullptr, nullptr, nullptr, 0);
    // routed experts (gather fused into staging): h -> hb[MPAD][1024], ytmp = h@w2, combine
    k_mm<DDIM, 0, true, false><<<dim3(IDIM / 64, NMT_R), 512, 0, stream>>>(
        xb, w13Tr, nullptr, nullptr, hb, IDIM, nullptr, off_pad, perm, zpad, 2 * IDIM * DDIM);
    k_mm<IDIM, 2, true, false><<<dim3(DDIM / 128, NMT_R), 512, 0, stream>>>(
        hb, w2T, nullptr, nullptr, ytmp, 0, nullptr, off_pad, nullptr, nullptr, DDIM * IDIM);
    k_combine<<<(T_TOK * DDIM / 4) / 256, 256, 0, stream>>>(ytmp, inv, wts, out);
}

// Round 12
// 359.843 us; speedup vs baseline: 1.0241x; 1.0241x over previous
//
#include <hip/hip_runtime.h>
#include <math.h>
#include <stdint.h>

// B=8,S=2048,D=512,I=1024,E=8,K=2,SH=2048 ; T=16384 tokens
#define T_TOK 16384
#define DDIM  512
#define IDIM  1024
#define NEXP  8
#define SHDIM 2048
#define MT_R  264                  // routed M-tiles (2T + 8*127 padded to 128)
#define MPAD  (MT_R * 128)         // 33792 padded routed rows
#define GBLK  256                  // k_gate blocks (64 tokens each)
#define NB    768                  // persistent GEMM blocks (3/CU x 256)
#define BPX   96                   // blocks per XCD (768/8)

typedef unsigned short u16;
typedef short bf16x8 __attribute__((ext_vector_type(8)));
typedef float f32x4 __attribute__((ext_vector_type(4)));

__device__ __forceinline__ u16 f2bf(float f) {
    unsigned u = __float_as_uint(f);
    u += 0x7FFF + ((u >> 16) & 1);   // round-to-nearest-even
    return (u16)(u >> 16);
}
__device__ __forceinline__ float bf2f(u16 h) {
    return __uint_as_float((unsigned)h << 16);
}

__device__ __forceinline__ void gload_lds16(const void* g, void* l) {
    __builtin_amdgcn_global_load_lds(
        (const __attribute__((address_space(1))) void*)g,
        (__attribute__((address_space(3))) void*)l, 16, 0, 0);
}

// 16B-slot swizzle, conflict-free (R10-verified: bank conflicts -> 0)
__device__ __forceinline__ int ksw(int r) { return (r >> 1) & 3; }

// ---------------- routing ----------------
// 64 tokens/block, 4 waves. No global atomics; fuses x->bf16 (writes xb).
__global__ __launch_bounds__(256) void k_gate(
    const float* __restrict__ x, const float* __restrict__ gw,
    int* __restrict__ topi, float* __restrict__ wts,
    int* __restrict__ pcnt, float* __restrict__ pps, u16* __restrict__ xb)
{
    __shared__ int   cnt[NEXP];
    __shared__ float ps[NEXP];
    const int tid = threadIdx.x;
    if (tid < NEXP) { cnt[tid] = 0; ps[tid] = 0.f; }
    __syncthreads();
    const int wid = tid >> 6, lane = tid & 63;

    const float4* gw4 = (const float4*)gw;
    float4 g0[NEXP], g1[NEXP];
#pragma unroll
    for (int e = 0; e < NEXP; e++) {
        g0[e] = gw4[e * 128 + lane];
        g1[e] = gw4[e * 128 + 64 + lane];
    }

    const int t0 = blockIdx.x * 64 + wid * 16;
    for (int u = 0; u < 16; u++) {
        int t = t0 + u;
        const float4* xr4 = (const float4*)(x + (size_t)t * DDIM);
        float4 v0 = xr4[lane];
        float4 v1 = xr4[64 + lane];
        ushort4 o0 = { f2bf(v0.x), f2bf(v0.y), f2bf(v0.z), f2bf(v0.w) };
        ushort4 o1 = { f2bf(v1.x), f2bf(v1.y), f2bf(v1.z), f2bf(v1.w) };
        ushort4* xbo = (ushort4*)(xb + (size_t)t * DDIM);
        xbo[lane] = o0;
        xbo[64 + lane] = o1;
        float acc[NEXP];
#pragma unroll
        for (int e = 0; e < NEXP; e++) {
            acc[e] = v0.x * g0[e].x + v0.y * g0[e].y + v0.z * g0[e].z + v0.w * g0[e].w
                   + v1.x * g1[e].x + v1.y * g1[e].y + v1.z * g1[e].z + v1.w * g1[e].w;
        }
#pragma unroll
        for (int e = 0; e < NEXP; e++) {
#pragma unroll
            for (int off = 32; off; off >>= 1) acc[e] += __shfl_xor(acc[e], off, 64);
        }
        if (lane == 0) {
            float s[NEXP];
#pragma unroll
            for (int e = 0; e < NEXP; e++) s[e] = 1.f / (1.f + expf(-acc[e]));
            int i1 = 0; float v1s = s[0];
#pragma unroll
            for (int e = 1; e < NEXP; e++) if (s[e] > v1s) { v1s = s[e]; i1 = e; }
            int i2 = -1; float v2s = -1.f;
#pragma unroll
            for (int e = 0; e < NEXP; e++) if (e != i1 && s[e] > v2s) { v2s = s[e]; i2 = e; }
            float inv = 1.f / (v1s + v2s);
            float wa = v1s * inv, wb = v2s * inv;  // ROUTE_SCALE = 1.0
            topi[2 * t] = i1; topi[2 * t + 1] = i2;
            wts[2 * t] = wa;  wts[2 * t + 1] = wb;
            atomicAdd(&cnt[i1], 1); atomicAdd(&cnt[i2], 1);   // LDS atomics
            atomicAdd(&ps[i1], wa); atomicAdd(&ps[i2], wb);
        }
    }
    __syncthreads();
    if (tid < NEXP) {
        pcnt[blockIdx.x * NEXP + tid] = cnt[tid];
        pps[blockIdx.x * NEXP + tid]  = ps[tid];
    }
}

// Reduce per-block partials; 128-padded exclusive prefix; aux loss; zero cursors.
__global__ void k_scan(const int* __restrict__ pcnt, const float* __restrict__ pps,
                       int* __restrict__ off_pad, float* __restrict__ out_loss,
                       int* __restrict__ cursors)
{
    __shared__ int   scnt[8][NEXP];
    __shared__ float sps[8][NEXP];
    int tid = threadIdx.x;
    if (tid < NEXP) cursors[tid] = 0;
    if (tid < 64) {
        int e = tid & 7, part = tid >> 3;
        int c = 0; float p = 0.f;
        for (int b = part * 32; b < part * 32 + 32; b++) {
            c += pcnt[b * NEXP + e];
            p += pps[b * NEXP + e];
        }
        scnt[part][e] = c; sps[part][e] = p;
    }
    __syncthreads();
    if (tid == 0) {
        int off = 0; float L = 0.f;
        for (int e = 0; e < NEXP; e++) {
            int c = 0; float p = 0.f;
            for (int q = 0; q < 8; q++) { c += scnt[q][e]; p += sps[q][e]; }
            off_pad[e] = off;
            off += (c + 127) & ~127;
            float f = (float)NEXP * (float)c / (float)(2 * T_TOK);
            L += f * (p / (float)T_TOK);
        }
        off_pad[NEXP] = off;
        out_loss[0] = L;
    }
}

// fills perm with -1; also zeroes the 512-elem bf16 zero-page
__global__ void k_fillperm(int* __restrict__ perm, u16* __restrict__ zpad) {
    int i = blockIdx.x * blockDim.x + threadIdx.x;
    if (i < MPAD) perm[i] = -1;
    if (blockIdx.x == 0 && threadIdx.x < 256) ((unsigned*)zpad)[threadIdx.x] = 0u;
}

// 256 tokens/block: LDS histogram -> one global atomicAdd per expert per block.
__global__ __launch_bounds__(256) void k_scatter(
    const int* __restrict__ topi, const float* __restrict__ wts,
    const int* __restrict__ off_pad, int* __restrict__ cursors,
    int* __restrict__ perm, float* __restrict__ pw, int* __restrict__ inv)
{
    __shared__ int lcnt[NEXP];
    __shared__ int lbase[NEXP];
    int tid = threadIdx.x;
    if (tid < NEXP) lcnt[tid] = 0;
    __syncthreads();
    int t = blockIdx.x * 256 + tid;
    int e0 = topi[2 * t], e1 = topi[2 * t + 1];
    int p0 = atomicAdd(&lcnt[e0], 1);
    int p1 = atomicAdd(&lcnt[e1], 1);
    __syncthreads();
    if (tid < NEXP) lbase[tid] = atomicAdd(&cursors[tid], lcnt[tid]);
    __syncthreads();
    int s0 = off_pad[e0] + lbase[e0] + p0;
    int s1 = off_pad[e1] + lbase[e1] + p1;
    perm[s0] = t; pw[s0] = wts[2 * t];
    perm[s1] = t; pw[s1] = wts[2 * t + 1];
    inv[2 * t] = s0; inv[2 * t + 1] = s1;
}

// dst[z][c][r] = bf16(src[z][r][c]) ; grid (C/64, R/64, nmat)
__global__ __launch_bounds__(256) void k_transpose(const float* __restrict__ src,
                                                   u16* __restrict__ dst, int R, int C)
{
    __shared__ u16 t[64][68];
    const float* s = src + (size_t)blockIdx.z * R * C;
    u16* d = dst + (size_t)blockIdx.z * R * C;
    int r0 = blockIdx.y * 64, c0 = blockIdx.x * 64;
    int tid = threadIdx.x;
    int lr = tid >> 4, lc = (tid & 15) * 4;
#pragma unroll
    for (int u = 0; u < 4; u++) {
        int r = lr + u * 16;
        float4 v = *(const float4*)&s[(size_t)(r0 + r) * C + c0 + lc];
        t[lc + 0][r] = f2bf(v.x);
        t[lc + 1][r] = f2bf(v.y);
        t[lc + 2][r] = f2bf(v.z);
        t[lc + 3][r] = f2bf(v.w);
    }
    __syncthreads();
    int wr = tid >> 4, wc = (tid & 15) * 4;
#pragma unroll
    for (int u = 0; u < 4; u++) {
        int c = wr + u * 16;
        ushort4 o = { t[c][wc], t[c][wc + 1], t[c][wc + 2], t[c][wc + 3] };
        *(ushort4*)&d[(size_t)(c0 + c) * R + r0 + wc] = o;
    }
}

// ---------------- persistent GEMM job sources ----------------
struct S1Src { const u16 *a0, *a1, *b1, *b3; int m0, n0; };
struct S2Src { const u16 *a0, *a1, *b0, *b1; int m0, n0; };

template<bool ROUTED>
__device__ __forceinline__ S1Src s1_build(
    int m0, int n0, int tk0, int tk1, int r0, int g0,
    const u16* Axb, const u16* B1t, const u16* B3t,
    const int* opad, const u16* zpad)
{
    S1Src s; s.m0 = m0; s.n0 = n0;
    const u16* b1 = B1t; const u16* b3 = B3t;
    if (ROUTED) {
        int e = 0;
#pragma unroll
        for (int k = 1; k < NEXP; k++) e += (opad[k] <= m0) ? 1 : 0;
        b1 += (size_t)e * IDIM * DDIM;
        b3 += (size_t)e * IDIM * DDIM;
        s.a0 = (tk0 >= 0 ? Axb + (size_t)tk0 * DDIM : zpad) + g0;
        s.a1 = (tk1 >= 0 ? Axb + (size_t)tk1 * DDIM : zpad) + g0;
    } else {
        s.a0 = Axb + (size_t)(m0 + r0) * DDIM + g0;
        s.a1 = Axb + (size_t)(m0 + 64 + r0) * DDIM + g0;
    }
    s.b1 = b1 + (size_t)(n0 + r0) * DDIM + g0;
    s.b3 = b3 + (size_t)(n0 + r0) * DDIM + g0;
    return s;
}

// ---------------- s1: persistent 128(M)x64(N) jobs, BK=32, 3-buf, counted vmcnt ----------------
// Per buffer 16KB: A 8KB | B1 4KB | B3 4KB.  Cross-job continuous tile stream.
template<bool ROUTED, bool BIAS, int GX>
__global__ __launch_bounds__(256, 3) void k_s1(
    const u16* __restrict__ Axb, const u16* __restrict__ B1t, const u16* __restrict__ B3t,
    const float* __restrict__ bias1, const float* __restrict__ bias3,
    u16* __restrict__ H, int ldh, const int* __restrict__ off_pad,
    const int* __restrict__ perm, const u16* __restrict__ zpad, int njobs_s)
{
    __shared__ __align__(16) unsigned char smem[3 * 16384];   // 48KB -> 3 blocks/CU
    int opad[NEXP + 1];
#pragma unroll
    for (int k = 0; k <= NEXP; k++) opad[k] = ROUTED ? off_pad[k] : 0;
    const int njobs = ROUTED ? ((opad[NEXP] >> 7) * GX) : njobs_s;
    const int b = blockIdx.x, xcd = b & 7, bx = b >> 3;
    const int q = njobs >> 3, r8 = njobs & 7;
    const int base = xcd < r8 ? xcd * (q + 1) : r8 * (q + 1) + (xcd - r8) * q;
    const int cnt = q + (xcd < r8 ? 1 : 0);
    if (bx >= cnt) return;

    const int tid = threadIdx.x;
    const int wid = tid >> 6, lane = tid & 63;
    const int fr = lane & 15, hi = lane >> 4;
    const int wrow = (wid >> 1) * 64, wcol = (wid & 1) * 32;
    const int r0 = tid >> 2;
    const int g0 = ((tid & 3) ^ ksw(r0)) * 8;    // ksw(r0)==ksw(r0+64)
    const int dstT = tid * 16;

    int aoff[4], boff[2];
#pragma unroll
    for (int i = 0; i < 4; i++) {
        int ar = wrow + i * 16 + fr;
        aoff[i] = ar * 64 + ((hi ^ ksw(ar)) << 4);
    }
#pragma unroll
    for (int j = 0; j < 2; j++) {
        int br = wcol + j * 16 + fr;
        boff[j] = br * 64 + ((hi ^ ksw(br)) << 4);
    }

#define S1_STAGE(S, kk, bb) do { \
        gload_lds16((S).a0 + (kk), (bb) + dstT); \
        gload_lds16((S).a1 + (kk), (bb) + 4096 + dstT); \
        gload_lds16((S).b1 + (kk), (bb) + 8192 + dstT); \
        gload_lds16((S).b3 + (kk), (bb) + 12288 + dstT); \
    } while (0)

    f32x4 acc1[4][2], acc3[4][2];
#pragma unroll
    for (int i = 0; i < 4; i++)
#pragma unroll
        for (int j = 0; j < 2; j++) { acc1[i][j] = {0.f, 0.f, 0.f, 0.f}; acc3[i][j] = {0.f, 0.f, 0.f, 0.f}; }

    const int NT = DDIM / 32;   // 16

    int lj = bx;
    int j0 = base + lj;
    int m0c = (j0 / GX) * 128, n0c = (j0 % GX) * 64;
    int tk0 = 0, tk1 = 0;
    if (ROUTED) { tk0 = perm[m0c + r0]; tk1 = perm[m0c + 64 + r0]; }
    S1Src cur = s1_build<ROUTED>(m0c, n0c, tk0, tk1, r0, g0, Axb, B1t, B3t, opad, zpad);
    S1_STAGE(cur, 0, smem);
    S1_STAGE(cur, 32, smem + 16384);

    int bufc = 0;
    while (true) {
        const bool hn = (lj + BPX) < cnt;
        int m0n = 0, n0n = 0, ntk0 = 0, ntk1 = 0;
        if (hn) {
            int jn = base + lj + BPX;
            m0n = (jn / GX) * 128; n0n = (jn % GX) * 64;
            if (ROUTED) { ntk0 = perm[m0n + r0]; ntk1 = perm[m0n + 64 + r0]; }  // issued early, used at t=NT-2
        }
        S1Src nxt;
        for (int t = 0; t < NT; t++) {
            int bufn = bufc + 2; if (bufn >= 3) bufn -= 3;
            unsigned char* bb = smem + bufn * 16384;
            if (t + 2 < NT) {
                S1_STAGE(cur, (t + 2) * 32, bb);
                asm volatile("s_waitcnt vmcnt(8)" ::: "memory");
            } else if (hn) {
                if (t + 2 == NT)
                    nxt = s1_build<ROUTED>(m0n, n0n, ntk0, ntk1, r0, g0, Axb, B1t, B3t, opad, zpad);
                S1_STAGE(nxt, (t + 2 - NT) * 32, bb);
                asm volatile("s_waitcnt vmcnt(8)" ::: "memory");
            } else if (t + 2 == NT) {
                asm volatile("s_waitcnt vmcnt(4)" ::: "memory");
            } else {
                asm volatile("s_waitcnt vmcnt(0)" ::: "memory");
            }
            __builtin_amdgcn_s_barrier();
            __builtin_amdgcn_sched_barrier(0);
            const unsigned char* cb = smem + bufc * 16384;
            bf16x8 av[4], b1v[2], b3v[2];
#pragma unroll
            for (int i = 0; i < 4; i++) av[i] = *(const bf16x8*)(cb + aoff[i]);
#pragma unroll
            for (int j = 0; j < 2; j++) {
                b1v[j] = *(const bf16x8*)(cb + 8192  + boff[j]);
                b3v[j] = *(const bf16x8*)(cb + 12288 + boff[j]);
            }
            __builtin_amdgcn_s_setprio(1);
#pragma unroll
            for (int i = 0; i < 4; i++)
#pragma unroll
                for (int j = 0; j < 2; j++) {
                    acc1[i][j] = __builtin_amdgcn_mfma_f32_16x16x32_bf16(av[i], b1v[j], acc1[i][j], 0, 0, 0);
                    acc3[i][j] = __builtin_amdgcn_mfma_f32_16x16x32_bf16(av[i], b3v[j], acc3[i][j], 0, 0, 0);
                }
            __builtin_amdgcn_s_setprio(0);
            __builtin_amdgcn_sched_barrier(0);
            __builtin_amdgcn_s_barrier();
            bufc++; if (bufc >= 3) bufc -= 3;
        }

        // epilogue for cur (runs while next job's tiles 0,1 are in flight)
        const int rr = hi * 4;
#pragma unroll
        for (int i = 0; i < 4; i++) {
#pragma unroll
            for (int j = 0; j < 2; j++) {
                int col = cur.n0 + wcol + j * 16 + fr;
                float bb1 = BIAS ? bias1[col] : 0.f;
                float bb3 = BIAS ? bias3[col] : 0.f;
#pragma unroll
                for (int r = 0; r < 4; r++) {
                    int row = cur.m0 + wrow + i * 16 + rr + r;
                    float v1 = acc1[i][j][r] + bb1;
                    float v3 = acc3[i][j][r] + bb3;
                    float hv = (v1 / (1.f + __expf(-v1))) * v3;
                    H[(size_t)row * ldh + col] = f2bf(hv);
                }
            }
        }
        if (!hn) break;
#pragma unroll
        for (int i = 0; i < 4; i++)
#pragma unroll
            for (int j = 0; j < 2; j++) { acc1[i][j] = {0.f, 0.f, 0.f, 0.f}; acc3[i][j] = {0.f, 0.f, 0.f, 0.f}; }
        cur = nxt;
        lj += BPX;
    }
#undef S1_STAGE
}

// ---------------- s2: persistent 128x128 jobs, BK=32, 3-buf, counted vmcnt ----------------
// EPI 1: out = C + bias2 (f32).  EPI 2: ytmp = bf16(C) (routed).
template<int K, int EPI, int GX>
__global__ __launch_bounds__(256, 3) void k_s2(
    const u16* __restrict__ A, const u16* __restrict__ Bt,
    const float* __restrict__ bias2, float* __restrict__ out,
    u16* __restrict__ ytmp, const int* __restrict__ off_pad, int njobs_s)
{
    constexpr bool ROUTED = (EPI == 2);
    __shared__ __align__(16) unsigned char smem[3 * 16384];
    int opad[NEXP + 1];
#pragma unroll
    for (int k = 0; k <= NEXP; k++) opad[k] = ROUTED ? off_pad[k] : 0;
    const int njobs = ROUTED ? ((opad[NEXP] >> 7) * GX) : njobs_s;
    const int b = blockIdx.x, xcd = b & 7, bx = b >> 3;
    const int q = njobs >> 3, r8 = njobs & 7;
    const int base = xcd < r8 ? xcd * (q + 1) : r8 * (q + 1) + (xcd - r8) * q;
    const int cnt = q + (xcd < r8 ? 1 : 0);
    if (bx >= cnt) return;

    const int tid = threadIdx.x;
    const int wid = tid >> 6, lane = tid & 63;
    const int fr = lane & 15, hi = lane >> 4;
    const int wrow = (wid >> 1) * 64, wcol = (wid & 1) * 64;
    const int r0 = tid >> 2;
    const int g0 = ((tid & 3) ^ ksw(r0)) * 8;
    const int dstT = tid * 16;

    int aoff[4], boff[4];
#pragma unroll
    for (int i = 0; i < 4; i++) {
        int ar = wrow + i * 16 + fr;
        aoff[i] = ar * 64 + ((hi ^ ksw(ar)) << 4);
        int br = wcol + i * 16 + fr;
        boff[i] = br * 64 + ((hi ^ ksw(br)) << 4);
    }

    auto build = [&](int m0, int n0) {
        S2Src s; s.m0 = m0; s.n0 = n0;
        const u16* bt = Bt;
        if (ROUTED) {
            int e = 0;
#pragma unroll
            for (int k = 1; k < NEXP; k++) e += (opad[k] <= m0) ? 1 : 0;
            bt += (size_t)e * DDIM * IDIM;
        }
        s.a0 = A  + (size_t)(m0 + r0) * K + g0;
        s.a1 = A  + (size_t)(m0 + 64 + r0) * K + g0;
        s.b0 = bt + (size_t)(n0 + r0) * K + g0;
        s.b1 = bt + (size_t)(n0 + 64 + r0) * K + g0;
        return s;
    };

#define S2_STAGE(S, kk, bb) do { \
        gload_lds16((S).a0 + (kk), (bb) + dstT); \
        gload_lds16((S).a1 + (kk), (bb) + 4096 + dstT); \
        gload_lds16((S).b0 + (kk), (bb) + 8192 + dstT); \
        gload_lds16((S).b1 + (kk), (bb) + 12288 + dstT); \
    } while (0)

    f32x4 acc[4][4];
#pragma unroll
    for (int i = 0; i < 4; i++)
#pragma unroll
        for (int j = 0; j < 4; j++) acc[i][j] = {0.f, 0.f, 0.f, 0.f};

    const int NT = K / 32;

    int lj = bx;
    int j0 = base + lj;
    S2Src cur = build((j0 / GX) * 128, (j0 % GX) * 128);
    S2_STAGE(cur, 0, smem);
    S2_STAGE(cur, 32, smem + 16384);

    int bufc = 0;
    while (true) {
        const bool hn = (lj + BPX) < cnt;
        int m0n = 0, n0n = 0;
        if (hn) {
            int jn = base + lj + BPX;
            m0n = (jn / GX) * 128; n0n = (jn % GX) * 128;
        }
        S2Src nxt;
        for (int t = 0; t < NT; t++) {
            int bufn = bufc + 2; if (bufn >= 3) bufn -= 3;
            unsigned char* bb = smem + bufn * 16384;
            if (t + 2 < NT) {
                S2_STAGE(cur, (t + 2) * 32, bb);
                asm volatile("s_waitcnt vmcnt(8)" ::: "memory");
            } else if (hn) {
                if (t + 2 == NT) nxt = build(m0n, n0n);
                S2_STAGE(nxt, (t + 2 - NT) * 32, bb);
                asm volatile("s_waitcnt vmcnt(8)" ::: "memory");
            } else if (t + 2 == NT) {
                asm volatile("s_waitcnt vmcnt(4)" ::: "memory");
            } else {
                asm volatile("s_waitcnt vmcnt(0)" ::: "memory");
            }
            __builtin_amdgcn_s_barrier();
            __builtin_amdgcn_sched_barrier(0);
            const unsigned char* cb = smem + bufc * 16384;
            bf16x8 av[4], bv[4];
#pragma unroll
            for (int i = 0; i < 4; i++) {
                av[i] = *(const bf16x8*)(cb + aoff[i]);
                bv[i] = *(const bf16x8*)(cb + 8192 + boff[i]);
            }
            __builtin_amdgcn_s_setprio(1);
#pragma unroll
            for (int i = 0; i < 4; i++)
#pragma unroll
                for (int j = 0; j < 4; j++)
                    acc[i][j] = __builtin_amdgcn_mfma_f32_16x16x32_bf16(av[i], bv[j], acc[i][j], 0, 0, 0);
            __builtin_amdgcn_s_setprio(0);
            __builtin_amdgcn_sched_barrier(0);
            __builtin_amdgcn_s_barrier();
            bufc++; if (bufc >= 3) bufc -= 3;
        }

        const int rr = hi * 4;
#pragma unroll
        for (int i = 0; i < 4; i++) {
#pragma unroll
            for (int r = 0; r < 4; r++) {
                int row = cur.m0 + wrow + i * 16 + rr + r;
#pragma unroll
                for (int j = 0; j < 4; j++) {
                    int col = cur.n0 + wcol + j * 16 + fr;
                    float v = acc[i][j][r];
                    if (EPI == 2) ytmp[(size_t)row * DDIM + col] = f2bf(v);
                    else          out[(size_t)row * DDIM + col] = v + bias2[col];
                }
            }
        }
        if (!hn) break;
#pragma unroll
        for (int i = 0; i < 4; i++)
#pragma unroll
            for (int j = 0; j < 4; j++) acc[i][j] = {0.f, 0.f, 0.f, 0.f};
        cur = nxt;
        lj += BPX;
    }
#undef S2_STAGE
}

// out[t] += wts[2t]*ytmp[inv[2t]] + wts[2t+1]*ytmp[inv[2t+1]]
__global__ __launch_bounds__(256) void k_combine(
    const u16* __restrict__ ytmp, const int* __restrict__ inv,
    const float* __restrict__ wts, float* __restrict__ out)
{
    int idx = blockIdx.x * 256 + threadIdx.x;
    int t = idx >> 7;
    int c = (idx & 127) * 4;
    int s0 = inv[2 * t], s1 = inv[2 * t + 1];
    float w0 = wts[2 * t], w1 = wts[2 * t + 1];
    ushort4 a = *(const ushort4*)&ytmp[(size_t)s0 * DDIM + c];
    ushort4 b = *(const ushort4*)&ytmp[(size_t)s1 * DDIM + c];
    float4 o = *(float4*)&out[(size_t)t * DDIM + c];
    o.x += w0 * bf2f(a.x) + w1 * bf2f(b.x);
    o.y += w0 * bf2f(a.y) + w1 * bf2f(b.y);
    o.z += w0 * bf2f(a.z) + w1 * bf2f(b.z);
    o.w += w0 * bf2f(a.w) + w1 * bf2f(b.w);
    *(float4*)&out[(size_t)t * DDIM + c] = o;
}

// ---------------- launch ----------------
extern "C" void kernel_launch(void* const* d_in, const int* in_sizes, int n_in,
                              void* d_out, int out_size, void* d_ws, size_t ws_size,
                              hipStream_t stream)
{
    const float* x   = (const float*)d_in[0];
    const float* gw  = (const float*)d_in[1];
    const float* w1  = (const float*)d_in[2];
    const float* w2  = (const float*)d_in[3];
    const float* w3  = (const float*)d_in[4];
    const float* sw1 = (const float*)d_in[5];
    const float* sb1 = (const float*)d_in[6];
    const float* sw2 = (const float*)d_in[7];
    const float* sb2 = (const float*)d_in[8];
    const float* sw3 = (const float*)d_in[9];
    const float* sb3 = (const float*)d_in[10];
    float* out = (float*)d_out;

    char* ws = (char*)d_ws;
    size_t off = 0;
    int*   topi    = (int*)(ws + off);   off += (size_t)2 * T_TOK * 4;
    float* wts     = (float*)(ws + off); off += (size_t)2 * T_TOK * 4;
    int*   perm    = (int*)(ws + off);   off += (size_t)MPAD * 4;
    float* pw      = (float*)(ws + off); off += (size_t)MPAD * 4;
    int*   cursors = (int*)(ws + off);   off += 256;
    int*   off_pad = (int*)(ws + off);   off += 256;
    int*   pcnt    = (int*)(ws + off);   off += (size_t)GBLK * NEXP * 4;
    float* pps     = (float*)(ws + off); off += (size_t)GBLK * NEXP * 4;
    int*   inv     = (int*)(ws + off);   off += (size_t)2 * T_TOK * 4;
    u16*   zpad    = (u16*)(ws + off);   off += 1024;
    u16*   xb      = (u16*)(ws + off);   off += (size_t)T_TOK * DDIM * 2;
    u16*   ytmp    = (u16*)(ws + off);   off += (size_t)MPAD * DDIM * 2;
    u16*   w1T     = (u16*)(ws + off);   off += (size_t)NEXP * IDIM * DDIM * 2;
    u16*   w3T     = (u16*)(ws + off);   off += (size_t)NEXP * IDIM * DDIM * 2;
    u16*   w2T     = (u16*)(ws + off);   off += (size_t)NEXP * DDIM * IDIM * 2;
    u16*   sw1T    = (u16*)(ws + off);   off += (size_t)SHDIM * DDIM * 2;
    u16*   sw3T    = (u16*)(ws + off);   off += (size_t)SHDIM * DDIM * 2;
    u16*   sw2T    = (u16*)(ws + off);   off += (size_t)DDIM * SHDIM * 2;
    u16*   hb      = (u16*)(ws + off);   off += (size_t)MPAD * IDIM * 2;   // shared h (16384x2048) fits too

    // routing
    k_gate<<<GBLK, 256, 0, stream>>>(x, gw, topi, wts, pcnt, pps, xb);
    k_scan<<<1, 64, 0, stream>>>(pcnt, pps, off_pad, out + (size_t)T_TOK * DDIM, cursors);
    k_fillperm<<<MPAD / 256, 256, 0, stream>>>(perm, zpad);
    k_scatter<<<T_TOK / 256, 256, 0, stream>>>(topi, wts, off_pad, cursors, perm, pw, inv);

    // weight transposes (fp32 -> bf16 [N][K])
    k_transpose<<<dim3(IDIM / 64, DDIM / 64, NEXP), 256, 0, stream>>>(w1, w1T, DDIM, IDIM);
    k_transpose<<<dim3(IDIM / 64, DDIM / 64, NEXP), 256, 0, stream>>>(w3, w3T, DDIM, IDIM);
    k_transpose<<<dim3(DDIM / 64, IDIM / 64, NEXP), 256, 0, stream>>>(w2, w2T, IDIM, DDIM);
    k_transpose<<<dim3(SHDIM / 64, DDIM / 64, 1), 256, 0, stream>>>(sw1, sw1T, DDIM, SHDIM);
    k_transpose<<<dim3(SHDIM / 64, DDIM / 64, 1), 256, 0, stream>>>(sw3, sw3T, DDIM, SHDIM);
    k_transpose<<<dim3(DDIM / 64, SHDIM / 64, 1), 256, 0, stream>>>(sw2, sw2T, SHDIM, DDIM);

    // shared expert (out = z)
    k_s1<false, true, SHDIM / 64><<<NB, 256, 0, stream>>>(
        xb, sw1T, sw3T, sb1, sb3, hb, SHDIM, off_pad, nullptr, nullptr,
        (T_TOK / 128) * (SHDIM / 64));
    k_s2<SHDIM, 1, DDIM / 128><<<NB, 256, 0, stream>>>(
        hb, sw2T, sb2, out, nullptr, off_pad, (T_TOK / 128) * (DDIM / 128));
    // routed experts (gather fused into s1 staging) -> ytmp, combine into out
    k_s1<true, false, IDIM / 64><<<NB, 256, 0, stream>>>(
        xb, w1T, w3T, nullptr, nullptr, hb, IDIM, off_pad, perm, zpad, 0);
    k_s2<IDIM, 2, DDIM / 128><<<NB, 256, 0, stream>>>(
        hb, w2T, nullptr, nullptr, ytmp, off_pad, 0);
    k_combine<<<(T_TOK * DDIM / 4) / 256, 256, 0, stream>>>(ytmp, inv, wts, out);
}